// Round 1
// baseline (3013.067 us; speedup 1.0000x reference)
//
#include <hip/hip_runtime.h>
#include <math.h>
#include <float.h>

#define NNODES 50000
#define NEDGES 800000
// feature dims: in=hid=out=128, heads=4, head_dim=32

// ---------------- atomic float max via int/uint reinterpret ----------------
__device__ __forceinline__ void atomicMaxF(float* addr, float v) {
    if (v >= 0.f) atomicMax((int*)addr, __float_as_int(v));
    else          atomicMin((unsigned int*)addr, __float_as_uint(v));
}

// ---------------- fill kernel ----------------
__global__ __launch_bounds__(256) void fill_kernel(float* __restrict__ p, float v, int n) {
    int i = blockIdx.x * 256 + threadIdx.x;
    if (i < n) p[i] = v;
}

// ---------------- GEMM + alpha: h = X@W ; alpha_s/d = <h, a_src/dst> -------
// X: [nrows,128], W: [128,128], out h: [nrows,128], alpha_*: [nrows,4]
#define BM 64
#define BK 32
__global__ __launch_bounds__(256) void gemm_alpha_kernel(
    const float* __restrict__ X, const float* __restrict__ W,
    const float* __restrict__ avs, const float* __restrict__ avd,
    float* __restrict__ Hh, float* __restrict__ alpha_s, float* __restrict__ alpha_d,
    int nrows)
{
    __shared__ float Xs[BK][BM];    // transposed X tile: Xs[k][row]
    __shared__ float Ws[BK][128];   // W tile: Ws[k][col]

    int t = threadIdx.x;
    int rg = t >> 4;          // 0..15 (row group of 4)
    int cg = t & 15;          // 0..15 (col group of 8)
    int row0 = rg * 4, col0 = cg * 8;
    int block_row = blockIdx.x * BM;

    float acc[4][8];
#pragma unroll
    for (int i = 0; i < 4; ++i)
#pragma unroll
        for (int j = 0; j < 8; ++j) acc[i][j] = 0.f;

    for (int k0 = 0; k0 < 128; k0 += BK) {
        // stage X tile (64 rows x 32 k), transposed: thread loads 8 floats of one row
        {
            int r  = t >> 2;              // 0..63
            int kk = (t & 3) * 8;         // 0,8,16,24
            int grow = block_row + r;
            float4 v0 = make_float4(0,0,0,0), v1 = make_float4(0,0,0,0);
            if (grow < nrows) {
                const float* p = X + (size_t)grow * 128 + k0 + kk;
                v0 = *(const float4*)p;
                v1 = *(const float4*)(p + 4);
            }
            Xs[kk+0][r] = v0.x; Xs[kk+1][r] = v0.y; Xs[kk+2][r] = v0.z; Xs[kk+3][r] = v0.w;
            Xs[kk+4][r] = v1.x; Xs[kk+5][r] = v1.y; Xs[kk+6][r] = v1.z; Xs[kk+7][r] = v1.w;
        }
        // stage W tile (32 k x 128 cols)
        {
            int kr = t >> 3;              // 0..31
            int cc = (t & 7) * 16;        // 0..112
            const float* p = W + (size_t)(k0 + kr) * 128 + cc;
            float4 w0 = ((const float4*)p)[0];
            float4 w1 = ((const float4*)p)[1];
            float4 w2 = ((const float4*)p)[2];
            float4 w3 = ((const float4*)p)[3];
            *(float4*)&Ws[kr][cc + 0]  = w0;
            *(float4*)&Ws[kr][cc + 4]  = w1;
            *(float4*)&Ws[kr][cc + 8]  = w2;
            *(float4*)&Ws[kr][cc + 12] = w3;
        }
        __syncthreads();
#pragma unroll
        for (int kk = 0; kk < BK; ++kk) {
            float4 a  = *(const float4*)&Xs[kk][row0];
            float4 w0 = *(const float4*)&Ws[kk][col0];
            float4 w1 = *(const float4*)&Ws[kk][col0 + 4];
            float av[4] = {a.x, a.y, a.z, a.w};
            float wv[8] = {w0.x, w0.y, w0.z, w0.w, w1.x, w1.y, w1.z, w1.w};
#pragma unroll
            for (int i = 0; i < 4; ++i)
#pragma unroll
                for (int j = 0; j < 8; ++j)
                    acc[i][j] = fmaf(av[i], wv[j], acc[i][j]);
        }
        __syncthreads();
    }

    // epilogue: write h and fused alpha dot products
    int head = cg >> 2;                        // col0/32
    const float* asrc = avs + head * 32 + (cg & 3) * 8;
    const float* adst = avd + head * 32 + (cg & 3) * 8;
#pragma unroll
    for (int i = 0; i < 4; ++i) {
        int grow = block_row + row0 + i;
        bool ok = (grow < nrows);
        if (ok) {
            float4 o0 = make_float4(acc[i][0], acc[i][1], acc[i][2], acc[i][3]);
            float4 o1 = make_float4(acc[i][4], acc[i][5], acc[i][6], acc[i][7]);
            *(float4*)&Hh[(size_t)grow * 128 + col0]     = o0;
            *(float4*)&Hh[(size_t)grow * 128 + col0 + 4] = o1;
        }
        float ps = 0.f, pd = 0.f;
#pragma unroll
        for (int j = 0; j < 8; ++j) {
            ps = fmaf(acc[i][j], asrc[j], ps);
            pd = fmaf(acc[i][j], adst[j], pd);
        }
        // reduce across the 4 col-groups of this head (lanes differ in bits 0,1)
        ps += __shfl_xor(ps, 1); ps += __shfl_xor(ps, 2);
        pd += __shfl_xor(pd, 1); pd += __shfl_xor(pd, 2);
        if (ok && (cg & 3) == 0) {
            alpha_s[grow * 4 + head] = ps;
            alpha_d[grow * 4 + head] = pd;
        }
    }
}

// ---------------- edge pass 1: logits + segment max ----------------
__global__ __launch_bounds__(256) void edge_logits_max_kernel(
    const int* __restrict__ src, const int* __restrict__ dst,
    const float* __restrict__ as_, const float* __restrict__ ad_,
    float* __restrict__ logits, float* __restrict__ smax)
{
    int i = blockIdx.x * 256 + threadIdx.x;
    if (i >= NEDGES * 4) return;
    int e = i >> 2, hh = i & 3;
    int s = src[e], d = dst[e];
    float l = as_[s * 4 + hh] + ad_[d * 4 + hh];
    l = (l >= 0.f) ? l : 0.2f * l;   // leaky relu
    logits[i] = l;
    atomicMaxF(&smax[d * 4 + hh], l);
}

// ---------------- edge pass 2: exp + segment sum (ex in-place) -------------
__global__ __launch_bounds__(256) void edge_expsum_kernel(
    const int* __restrict__ dst,
    float* __restrict__ logits,       // in: logits, out: ex
    const float* __restrict__ smax, float* __restrict__ den)
{
    int i = blockIdx.x * 256 + threadIdx.x;
    if (i >= NEDGES * 4) return;
    int e = i >> 2, hh = i & 3;
    int d = dst[e];
    float ex = expf(logits[i] - smax[d * 4 + hh]);
    logits[i] = ex;
    atomicAdd(&den[d * 4 + hh], ex);
}

// ---------------- edge pass 3: scatter att * h[src] into acc ---------------
__global__ __launch_bounds__(256) void edge_scatter_kernel(
    const int* __restrict__ src, const int* __restrict__ dst,
    const float* __restrict__ exb, const float* __restrict__ den,
    const float* __restrict__ hbuf, float* __restrict__ acc)
{
    int i = blockIdx.x * 256 + threadIdx.x;   // over E*32, 4 floats per thread
    if (i >= NEDGES * 32) return;
    int e = i >> 5;
    int q = (i & 31) * 4;       // feature offset 0..124
    int hh = q >> 5;            // head
    int s = src[e], d = dst[e];
    float att = exb[e * 4 + hh] / fmaxf(den[d * 4 + hh], 1e-16f);
    float4 hv = *(const float4*)(hbuf + (size_t)s * 128 + q);
    float* po = acc + (size_t)d * 128 + q;
    atomicAdd(po + 0, att * hv.x);
    atomicAdd(po + 1, att * hv.y);
    atomicAdd(po + 2, att * hv.z);
    atomicAdd(po + 3, att * hv.w);
}

// ---------------- finalize: out = elu(acc + b) ----------------
__global__ __launch_bounds__(256) void finalize_kernel(
    const float* __restrict__ acc, const float* __restrict__ b,
    float* __restrict__ out)
{
    int i = blockIdx.x * 256 + threadIdx.x;
    if (i >= NNODES * 128) return;
    float x = acc[i] + b[i & 127];
    out[i] = (x > 0.f) ? x : expm1f(x);
}

extern "C" void kernel_launch(void* const* d_in, const int* in_sizes, int n_in,
                              void* d_out, int out_size, void* d_ws, size_t ws_size,
                              hipStream_t stream) {
    const float* X    = (const float*)d_in[0];
    const int*   ei   = (const int*)d_in[1];
    const float* W0   = (const float*)d_in[2];
    const float* as0  = (const float*)d_in[3];
    const float* ad0  = (const float*)d_in[4];
    const float* b0   = (const float*)d_in[5];
    const float* W1   = (const float*)d_in[6];
    const float* as1  = (const float*)d_in[7];
    const float* ad1  = (const float*)d_in[8];
    const float* b1   = (const float*)d_in[9];

    const int* srcp = ei;            // edge_index[0]
    const int* dstp = ei + NEDGES;   // edge_index[1]

    float* ws = (float*)d_ws;
    float* h    = ws;                        // 6,400,000
    float* acc  = h    + 6400000;            // 6,400,000
    float* hout = acc  + 6400000;            // 6,400,000 (layer-1 output)
    float* elog = hout + 6400000;            // 3,200,000 (logits -> ex)
    float* as_  = elog + 3200000;            // 200,000
    float* ad_  = as_  + 200000;             // 200,000
    float* smax = ad_  + 200000;             // 200,000
    float* den  = smax + 200000;             // 200,000

    for (int layer = 0; layer < 2; ++layer) {
        const float* Hin = layer ? hout : X;
        const float* W   = layer ? W1  : W0;
        const float* avs = layer ? as1 : as0;
        const float* avd = layer ? ad1 : ad0;
        const float* bv  = layer ? b1  : b0;
        float* outp      = layer ? (float*)d_out : hout;

        hipMemsetAsync(acc, 0, (size_t)NNODES * 128 * sizeof(float), stream);
        hipMemsetAsync(den, 0, (size_t)NNODES * 4 * sizeof(float), stream);
        fill_kernel<<<(NNODES * 4 + 255) / 256, 256, 0, stream>>>(smax, -INFINITY, NNODES * 4);

        gemm_alpha_kernel<<<(NNODES + BM - 1) / BM, 256, 0, stream>>>(
            Hin, W, avs, avd, h, as_, ad_, NNODES);

        edge_logits_max_kernel<<<(NEDGES * 4 + 255) / 256, 256, 0, stream>>>(
            srcp, dstp, as_, ad_, elog, smax);

        edge_expsum_kernel<<<(NEDGES * 4 + 255) / 256, 256, 0, stream>>>(
            dstp, elog, smax, den);

        edge_scatter_kernel<<<(NEDGES * 32 + 255) / 256, 256, 0, stream>>>(
            srcp, dstp, elog, den, h, acc);

        finalize_kernel<<<(NNODES * 128 + 255) / 256, 256, 0, stream>>>(acc, bv, outp);
    }
}

// Round 2
// 508.590 us; speedup vs baseline: 5.9244x; 5.9244x over previous
//
#include <hip/hip_runtime.h>
#include <math.h>
#include <float.h>

#define NNODES 50000
#define NEDGES 800000
// feature dims: in=hid=out=128, heads=4, head_dim=32

// ---------------- CSR build ----------------
__global__ __launch_bounds__(256) void hist_kernel(const int* __restrict__ dst,
                                                   int* __restrict__ deg) {
    int e = blockIdx.x * 256 + threadIdx.x;
    if (e < NEDGES) atomicAdd(&deg[dst[e]], 1);
}

// single block, 1024 threads: exclusive scan of deg -> roff[0..N], cursor=roff
__global__ __launch_bounds__(1024) void scan_kernel(const int* __restrict__ deg,
                                                    int* __restrict__ roff,
                                                    int* __restrict__ cursor) {
    __shared__ int part[1024];
    int t = threadIdx.x;
    const int CH = (NNODES + 1023) / 1024;   // 49
    int base = t * CH;
    int s = 0;
    for (int i = 0; i < CH; ++i) {
        int idx = base + i;
        if (idx < NNODES) s += deg[idx];
    }
    part[t] = s;
    __syncthreads();
    for (int off = 1; off < 1024; off <<= 1) {
        int v = (t >= off) ? part[t - off] : 0;
        __syncthreads();
        part[t] += v;
        __syncthreads();
    }
    int run = (t == 0) ? 0 : part[t - 1];    // exclusive prefix
    for (int i = 0; i < CH; ++i) {
        int idx = base + i;
        if (idx < NNODES) {
            roff[idx] = run;
            cursor[idx] = run;
            run += deg[idx];
        }
    }
    if (t == 1023) roff[NNODES] = part[1023];
}

__global__ __launch_bounds__(256) void bucket_kernel(const int* __restrict__ src,
                                                     const int* __restrict__ dst,
                                                     int* __restrict__ cursor,
                                                     int* __restrict__ csr_src) {
    int e = blockIdx.x * 256 + threadIdx.x;
    if (e >= NEDGES) return;
    int d = dst[e];
    int pos = atomicAdd(&cursor[d], 1);
    csr_src[pos] = src[e];
}

// ---------------- GEMM + alpha: h = X@W ; alpha_s/d = <h, a_src/dst> -------
#define BM 64
#define BK 32
__global__ __launch_bounds__(256) void gemm_alpha_kernel(
    const float* __restrict__ X, const float* __restrict__ W,
    const float* __restrict__ avs, const float* __restrict__ avd,
    float* __restrict__ Hh, float* __restrict__ alpha_s, float* __restrict__ alpha_d,
    int nrows)
{
    __shared__ float Xs[BK][BM];    // transposed X tile: Xs[k][row]
    __shared__ float Ws[BK][128];   // W tile: Ws[k][col]

    int t = threadIdx.x;
    int rg = t >> 4;          // 0..15 (row group of 4)
    int cg = t & 15;          // 0..15 (col group of 8)
    int row0 = rg * 4, col0 = cg * 8;
    int block_row = blockIdx.x * BM;

    float acc[4][8];
#pragma unroll
    for (int i = 0; i < 4; ++i)
#pragma unroll
        for (int j = 0; j < 8; ++j) acc[i][j] = 0.f;

    for (int k0 = 0; k0 < 128; k0 += BK) {
        {
            int r  = t >> 2;              // 0..63
            int kk = (t & 3) * 8;         // 0,8,16,24
            int grow = block_row + r;
            float4 v0 = make_float4(0,0,0,0), v1 = make_float4(0,0,0,0);
            if (grow < nrows) {
                const float* p = X + (size_t)grow * 128 + k0 + kk;
                v0 = *(const float4*)p;
                v1 = *(const float4*)(p + 4);
            }
            Xs[kk+0][r] = v0.x; Xs[kk+1][r] = v0.y; Xs[kk+2][r] = v0.z; Xs[kk+3][r] = v0.w;
            Xs[kk+4][r] = v1.x; Xs[kk+5][r] = v1.y; Xs[kk+6][r] = v1.z; Xs[kk+7][r] = v1.w;
        }
        {
            int kr = t >> 3;              // 0..31
            int cc = (t & 7) * 16;        // 0..112
            const float* p = W + (size_t)(k0 + kr) * 128 + cc;
            float4 w0 = ((const float4*)p)[0];
            float4 w1 = ((const float4*)p)[1];
            float4 w2 = ((const float4*)p)[2];
            float4 w3 = ((const float4*)p)[3];
            *(float4*)&Ws[kr][cc + 0]  = w0;
            *(float4*)&Ws[kr][cc + 4]  = w1;
            *(float4*)&Ws[kr][cc + 8]  = w2;
            *(float4*)&Ws[kr][cc + 12] = w3;
        }
        __syncthreads();
#pragma unroll
        for (int kk = 0; kk < BK; ++kk) {
            float4 a  = *(const float4*)&Xs[kk][row0];
            float4 w0 = *(const float4*)&Ws[kk][col0];
            float4 w1 = *(const float4*)&Ws[kk][col0 + 4];
            float av[4] = {a.x, a.y, a.z, a.w};
            float wv[8] = {w0.x, w0.y, w0.z, w0.w, w1.x, w1.y, w1.z, w1.w};
#pragma unroll
            for (int i = 0; i < 4; ++i)
#pragma unroll
                for (int j = 0; j < 8; ++j)
                    acc[i][j] = fmaf(av[i], wv[j], acc[i][j]);
        }
        __syncthreads();
    }

    int head = cg >> 2;
    const float* asrc = avs + head * 32 + (cg & 3) * 8;
    const float* adst = avd + head * 32 + (cg & 3) * 8;
#pragma unroll
    for (int i = 0; i < 4; ++i) {
        int grow = block_row + row0 + i;
        bool ok = (grow < nrows);
        if (ok) {
            float4 o0 = make_float4(acc[i][0], acc[i][1], acc[i][2], acc[i][3]);
            float4 o1 = make_float4(acc[i][4], acc[i][5], acc[i][6], acc[i][7]);
            *(float4*)&Hh[(size_t)grow * 128 + col0]     = o0;
            *(float4*)&Hh[(size_t)grow * 128 + col0 + 4] = o1;
        }
        float ps = 0.f, pd = 0.f;
#pragma unroll
        for (int j = 0; j < 8; ++j) {
            ps = fmaf(acc[i][j], asrc[j], ps);
            pd = fmaf(acc[i][j], adst[j], pd);
        }
        ps += __shfl_xor(ps, 1); ps += __shfl_xor(ps, 2);
        pd += __shfl_xor(pd, 1); pd += __shfl_xor(pd, 2);
        if (ok && (cg & 3) == 0) {
            alpha_s[grow * 4 + head] = ps;
            alpha_d[grow * 4 + head] = pd;
        }
    }
}

// ---------------- fused per-node softmax + gather + bias + ELU -------------
// one block (128 threads) per destination node; thread t owns feature t.
__global__ __launch_bounds__(128) void node_gather_kernel(
    const int* __restrict__ csr_src, const int* __restrict__ roff,
    const float* __restrict__ alpha_s, const float* __restrict__ alpha_d,
    const float* __restrict__ hbuf, const float* __restrict__ b,
    float* __restrict__ out)
{
    int d = blockIdx.x;
    int t = threadIdx.x;
    int h = t >> 5;                     // head 0..3
    float ad = alpha_d[d * 4 + h];
    int beg = roff[d], end = roff[d + 1];

    float m = -INFINITY, den = 0.f, acc = 0.f;
    for (int i = beg; i < end; ++i) {
        int s = csr_src[i];
        float l = alpha_s[s * 4 + h] + ad;
        l = (l >= 0.f) ? l : 0.2f * l;          // leaky relu
        float nm = fmaxf(m, l);
        float scale = expf(m - nm);             // first iter: exp(-inf)=0
        float w = expf(l - nm);
        float hv = hbuf[(size_t)s * 128 + t];
        den = den * scale + w;
        acc = acc * scale + w * hv;
        m = nm;
    }
    float x = acc / fmaxf(den, 1e-16f) + b[t];
    out[(size_t)d * 128 + t] = (x > 0.f) ? x : expm1f(x);
}

extern "C" void kernel_launch(void* const* d_in, const int* in_sizes, int n_in,
                              void* d_out, int out_size, void* d_ws, size_t ws_size,
                              hipStream_t stream) {
    const float* X    = (const float*)d_in[0];
    const int*   ei   = (const int*)d_in[1];
    const float* W0   = (const float*)d_in[2];
    const float* as0  = (const float*)d_in[3];
    const float* ad0  = (const float*)d_in[4];
    const float* b0   = (const float*)d_in[5];
    const float* W1   = (const float*)d_in[6];
    const float* as1  = (const float*)d_in[7];
    const float* ad1  = (const float*)d_in[8];
    const float* b1   = (const float*)d_in[9];

    const int* srcp = ei;            // edge_index[0]
    const int* dstp = ei + NEDGES;   // edge_index[1]

    float* ws = (float*)d_ws;
    float* h    = ws;                        // 6,400,000 floats
    float* hout = h    + 6400000;            // 6,400,000
    float* as_  = hout + 6400000;            // 200,000
    float* ad_  = as_  + 200000;             // 200,000
    int*   deg     = (int*)(ad_ + 200000);   // 50,000 ints
    int*   roff    = deg + 50000;            // 50,001
    int*   cursor  = roff + 50001;           // 50,000
    int*   csr_src = cursor + 50000;         // 800,000

    // ---- CSR build (by destination) ----
    hipMemsetAsync(deg, 0, NNODES * sizeof(int), stream);
    hist_kernel<<<(NEDGES + 255) / 256, 256, 0, stream>>>(dstp, deg);
    scan_kernel<<<1, 1024, 0, stream>>>(deg, roff, cursor);
    bucket_kernel<<<(NEDGES + 255) / 256, 256, 0, stream>>>(srcp, dstp, cursor, csr_src);

    for (int layer = 0; layer < 2; ++layer) {
        const float* Hin = layer ? hout : X;
        const float* W   = layer ? W1  : W0;
        const float* avs = layer ? as1 : as0;
        const float* avd = layer ? ad1 : ad0;
        const float* bv  = layer ? b1  : b0;
        float* outp      = layer ? (float*)d_out : hout;

        gemm_alpha_kernel<<<(NNODES + BM - 1) / BM, 256, 0, stream>>>(
            Hin, W, avs, avd, h, as_, ad_, NNODES);

        node_gather_kernel<<<NNODES, 128, 0, stream>>>(
            csr_src, roff, as_, ad_, h, bv, outp);
    }
}

// Round 3
// 338.064 us; speedup vs baseline: 8.9127x; 1.5044x over previous
//
#include <hip/hip_runtime.h>
#include <math.h>
#include <float.h>

#define NNODES 50000
#define NEDGES 800000
#define NSCANB ((NNODES + 255) / 256)   // 196
// feature dims: in=hid=out=128, heads=4, head_dim=32

// ---------------- CSR build ----------------
__global__ __launch_bounds__(256) void hist_kernel(const int* __restrict__ dst,
                                                   int* __restrict__ deg) {
    int e = blockIdx.x * 256 + threadIdx.x;
    if (e < NEDGES) atomicAdd(&deg[dst[e]], 1);
}

// stage 1: per-block (256-elem chunk) sums
__global__ __launch_bounds__(256) void scan1_kernel(const int* __restrict__ deg,
                                                    int* __restrict__ bsum) {
    int i = blockIdx.x * 256 + threadIdx.x;
    int t = threadIdx.x, lane = t & 63, w = t >> 6;
    int v = (i < NNODES) ? deg[i] : 0;
    int x = v;
#pragma unroll
    for (int off = 1; off < 64; off <<= 1) x += __shfl_xor(x, off);
    __shared__ int wtot[4];
    if (lane == 0) wtot[w] = x;
    __syncthreads();
    if (t == 0) bsum[blockIdx.x] = wtot[0] + wtot[1] + wtot[2] + wtot[3];
}

// stage 2: one block scans the 196 block sums (exclusive) + writes total
__global__ __launch_bounds__(256) void scan2_kernel(const int* __restrict__ bsum,
                                                    int* __restrict__ boff,
                                                    int* __restrict__ roff) {
    __shared__ int s[256];
    int t = threadIdx.x;
    int v = (t < NSCANB) ? bsum[t] : 0;
    s[t] = v;
    __syncthreads();
    for (int off = 1; off < 256; off <<= 1) {
        int y = (t >= off) ? s[t - off] : 0;
        __syncthreads();
        s[t] += y;
        __syncthreads();
    }
    if (t < NSCANB) boff[t] = s[t] - v;          // exclusive prefix
    if (t == 255) roff[NNODES] = s[255];         // grand total (=NEDGES)
}

// stage 3: local exclusive scan within each 256-chunk, add block offset
__global__ __launch_bounds__(256) void scan3_kernel(const int* __restrict__ deg,
                                                    const int* __restrict__ boff,
                                                    int* __restrict__ roff,
                                                    int* __restrict__ cursor) {
    int i = blockIdx.x * 256 + threadIdx.x;
    int t = threadIdx.x, lane = t & 63, w = t >> 6;
    int v = (i < NNODES) ? deg[i] : 0;
    int x = v;
#pragma unroll
    for (int off = 1; off < 64; off <<= 1) {
        int y = __shfl_up(x, off, 64);
        if (lane >= off) x += y;
    }
    __shared__ int wtot[4];
    if (lane == 63) wtot[w] = x;
    __syncthreads();
    int wpre = 0;
#pragma unroll
    for (int j = 0; j < 4; ++j) if (j < w) wpre += wtot[j];
    int ex = boff[blockIdx.x] + wpre + x - v;    // exclusive prefix
    if (i < NNODES) { roff[i] = ex; cursor[i] = ex; }
}

__global__ __launch_bounds__(256) void bucket_kernel(const int* __restrict__ src,
                                                     const int* __restrict__ dst,
                                                     int* __restrict__ cursor,
                                                     int* __restrict__ csr_src) {
    int e = blockIdx.x * 256 + threadIdx.x;
    if (e >= NEDGES) return;
    int d = dst[e];
    int pos = atomicAdd(&cursor[d], 1);
    csr_src[pos] = src[e];
}

// ---------------- GEMM + alpha: h = X@W ; alpha_s/d = <h, a_src/dst> -------
#define BM 64
#define BK 32
__global__ __launch_bounds__(256) void gemm_alpha_kernel(
    const float* __restrict__ X, const float* __restrict__ W,
    const float* __restrict__ avs, const float* __restrict__ avd,
    float* __restrict__ Hh, float* __restrict__ alpha_s, float* __restrict__ alpha_d,
    int nrows)
{
    __shared__ float Xs[BK][BM];    // transposed X tile: Xs[k][row]
    __shared__ float Ws[BK][128];   // W tile: Ws[k][col]

    int t = threadIdx.x;
    int rg = t >> 4;          // 0..15
    int cg = t & 15;          // 0..15
    int row0 = rg * 4, col0 = cg * 8;
    int block_row = blockIdx.x * BM;

    float acc[4][8];
#pragma unroll
    for (int i = 0; i < 4; ++i)
#pragma unroll
        for (int j = 0; j < 8; ++j) acc[i][j] = 0.f;

    for (int k0 = 0; k0 < 128; k0 += BK) {
        {
            int r  = t >> 2;
            int kk = (t & 3) * 8;
            int grow = block_row + r;
            float4 v0 = make_float4(0,0,0,0), v1 = make_float4(0,0,0,0);
            if (grow < nrows) {
                const float* p = X + (size_t)grow * 128 + k0 + kk;
                v0 = *(const float4*)p;
                v1 = *(const float4*)(p + 4);
            }
            Xs[kk+0][r] = v0.x; Xs[kk+1][r] = v0.y; Xs[kk+2][r] = v0.z; Xs[kk+3][r] = v0.w;
            Xs[kk+4][r] = v1.x; Xs[kk+5][r] = v1.y; Xs[kk+6][r] = v1.z; Xs[kk+7][r] = v1.w;
        }
        {
            int kr = t >> 3;
            int cc = (t & 7) * 16;
            const float* p = W + (size_t)(k0 + kr) * 128 + cc;
            float4 w0 = ((const float4*)p)[0];
            float4 w1 = ((const float4*)p)[1];
            float4 w2 = ((const float4*)p)[2];
            float4 w3 = ((const float4*)p)[3];
            *(float4*)&Ws[kr][cc + 0]  = w0;
            *(float4*)&Ws[kr][cc + 4]  = w1;
            *(float4*)&Ws[kr][cc + 8]  = w2;
            *(float4*)&Ws[kr][cc + 12] = w3;
        }
        __syncthreads();
#pragma unroll
        for (int kk = 0; kk < BK; ++kk) {
            float4 a  = *(const float4*)&Xs[kk][row0];
            float4 w0 = *(const float4*)&Ws[kk][col0];
            float4 w1 = *(const float4*)&Ws[kk][col0 + 4];
            float av[4] = {a.x, a.y, a.z, a.w};
            float wv[8] = {w0.x, w0.y, w0.z, w0.w, w1.x, w1.y, w1.z, w1.w};
#pragma unroll
            for (int i = 0; i < 4; ++i)
#pragma unroll
                for (int j = 0; j < 8; ++j)
                    acc[i][j] = fmaf(av[i], wv[j], acc[i][j]);
        }
        __syncthreads();
    }

    int head = cg >> 2;
    const float* asrc = avs + head * 32 + (cg & 3) * 8;
    const float* adst = avd + head * 32 + (cg & 3) * 8;
#pragma unroll
    for (int i = 0; i < 4; ++i) {
        int grow = block_row + row0 + i;
        bool ok = (grow < nrows);
        if (ok) {
            float4 o0 = make_float4(acc[i][0], acc[i][1], acc[i][2], acc[i][3]);
            float4 o1 = make_float4(acc[i][4], acc[i][5], acc[i][6], acc[i][7]);
            *(float4*)&Hh[(size_t)grow * 128 + col0]     = o0;
            *(float4*)&Hh[(size_t)grow * 128 + col0 + 4] = o1;
        }
        float ps = 0.f, pd = 0.f;
#pragma unroll
        for (int j = 0; j < 8; ++j) {
            ps = fmaf(acc[i][j], asrc[j], ps);
            pd = fmaf(acc[i][j], adst[j], pd);
        }
        ps += __shfl_xor(ps, 1); ps += __shfl_xor(ps, 2);
        pd += __shfl_xor(pd, 1); pd += __shfl_xor(pd, 2);
        if (ok && (cg & 3) == 0) {
            alpha_s[grow * 4 + head] = ps;
            alpha_d[grow * 4 + head] = pd;
        }
    }
}

// ---------------- fused per-node softmax + gather + bias + ELU -------------
// one block (128 threads) per destination node; thread t owns feature t.
__global__ __launch_bounds__(128) void node_gather_kernel(
    const int* __restrict__ csr_src, const int* __restrict__ roff,
    const float* __restrict__ alpha_s, const float* __restrict__ alpha_d,
    const float* __restrict__ hbuf, const float* __restrict__ b,
    float* __restrict__ out)
{
    int d = blockIdx.x;
    int t = threadIdx.x;
    int h = t >> 5;                     // head 0..3
    float ad = alpha_d[d * 4 + h];
    int beg = roff[d], end = roff[d + 1];

    float m = -INFINITY, den = 0.f, acc = 0.f;
    int i = beg;
    for (; i + 1 < end; i += 2) {
        int s0 = csr_src[i];
        int s1 = csr_src[i + 1];
        float l0 = alpha_s[s0 * 4 + h] + ad;
        float l1 = alpha_s[s1 * 4 + h] + ad;
        l0 = (l0 >= 0.f) ? l0 : 0.2f * l0;
        l1 = (l1 >= 0.f) ? l1 : 0.2f * l1;
        float hv0 = hbuf[(size_t)s0 * 128 + t];
        float hv1 = hbuf[(size_t)s1 * 128 + t];
        float nm = fmaxf(m, fmaxf(l0, l1));
        float scale = expf(m - nm);              // first iter: exp(-inf)=0
        float w0 = expf(l0 - nm);
        float w1 = expf(l1 - nm);
        den = den * scale + w0 + w1;
        acc = acc * scale + w0 * hv0 + w1 * hv1;
        m = nm;
    }
    if (i < end) {
        int s0 = csr_src[i];
        float l0 = alpha_s[s0 * 4 + h] + ad;
        l0 = (l0 >= 0.f) ? l0 : 0.2f * l0;
        float hv0 = hbuf[(size_t)s0 * 128 + t];
        float nm = fmaxf(m, l0);
        float scale = expf(m - nm);
        float w0 = expf(l0 - nm);
        den = den * scale + w0;
        acc = acc * scale + w0 * hv0;
        m = nm;
    }
    float x = acc / fmaxf(den, 1e-16f) + b[t];
    out[(size_t)d * 128 + t] = (x > 0.f) ? x : expm1f(x);
}

extern "C" void kernel_launch(void* const* d_in, const int* in_sizes, int n_in,
                              void* d_out, int out_size, void* d_ws, size_t ws_size,
                              hipStream_t stream) {
    const float* X    = (const float*)d_in[0];
    const int*   ei   = (const int*)d_in[1];
    const float* W0   = (const float*)d_in[2];
    const float* as0  = (const float*)d_in[3];
    const float* ad0  = (const float*)d_in[4];
    const float* b0   = (const float*)d_in[5];
    const float* W1   = (const float*)d_in[6];
    const float* as1  = (const float*)d_in[7];
    const float* ad1  = (const float*)d_in[8];
    const float* b1   = (const float*)d_in[9];

    const int* srcp = ei;            // edge_index[0]
    const int* dstp = ei + NEDGES;   // edge_index[1]

    float* ws = (float*)d_ws;
    float* h    = ws;                        // 6,400,000 floats
    float* hout = h    + 6400000;            // 6,400,000
    float* as_  = hout + 6400000;            // 200,000
    float* ad_  = as_  + 200000;             // 200,000
    int*   deg     = (int*)(ad_ + 200000);   // 50,000 ints
    int*   roff    = deg + 50000;            // 50,001
    int*   cursor  = roff + 50001;           // 50,000
    int*   csr_src = cursor + 50000;         // 800,000
    int*   bsum    = csr_src + 800000;       // 196
    int*   boff    = bsum + NSCANB;          // 196

    // ---- CSR build (by destination) ----
    hipMemsetAsync(deg, 0, NNODES * sizeof(int), stream);
    hist_kernel<<<(NEDGES + 255) / 256, 256, 0, stream>>>(dstp, deg);
    scan1_kernel<<<NSCANB, 256, 0, stream>>>(deg, bsum);
    scan2_kernel<<<1, 256, 0, stream>>>(bsum, boff, roff);
    scan3_kernel<<<NSCANB, 256, 0, stream>>>(deg, boff, roff, cursor);
    bucket_kernel<<<(NEDGES + 255) / 256, 256, 0, stream>>>(srcp, dstp, cursor, csr_src);

    for (int layer = 0; layer < 2; ++layer) {
        const float* Hin = layer ? hout : X;
        const float* W   = layer ? W1  : W0;
        const float* avs = layer ? as1 : as0;
        const float* avd = layer ? ad1 : ad0;
        const float* bv  = layer ? b1  : b0;
        float* outp      = layer ? (float*)d_out : hout;

        gemm_alpha_kernel<<<(NNODES + BM - 1) / BM, 256, 0, stream>>>(
            Hin, W, avs, avd, h, as_, ad_, NNODES);

        node_gather_kernel<<<NNODES, 128, 0, stream>>>(
            csr_src, roff, as_, ad_, h, bv, outp);
    }
}